// Round 11
// baseline (2329.760 us; speedup 1.0000x reference)
//
#include <hip/hip_runtime.h>
#include <hip/hip_bf16.h>
#include <stdint.h>
#include <math.h>

// ---------------------------------------------------------------------------
// SymmetricRBM: CD loss, 10-step Gibbs, JAX-threefry-exact RNG.
// B=8192, V=H=1024. R10->R11: TENSILE-STYLE two-stage staging.
//   buffer_load -> VGPR (3-stage rotating pipeline) -> ds_write -> LDS dbuf.
//   In-flight global loads target REGISTERS, so __syncthreads only needs
//   lgkmcnt(0) -- no vmcnt(0) drain (that drain is forced only by
//   global_load_lds, which all six prior structures used). The vmcnt wait
//   lands at the ds_write consuming data loaded 2 iters earlier (vmcnt(8)).
//   Tile 128x128xBK32, 256 thr, LDS 32KB/block, R10-verified swizzle.
//   K-order unchanged -> bit-exact chain (absmax 0.0 is the oracle).
// ---------------------------------------------------------------------------

static constexpr int Bn = 8192;
static constexpr int Vn = 1024;
static constexpr int Hn = 1024;
static constexpr int KSTEPS = 10;

typedef _Float16 f16;
typedef f16   f16x4 __attribute__((ext_vector_type(4)));
typedef f16   f16x8 __attribute__((ext_vector_type(8)));
typedef float f32x4 __attribute__((ext_vector_type(4)));

// ------------------------- Threefry-2x32 (JAX-exact) -----------------------
__device__ __forceinline__ uint32_t rotl32(uint32_t x, int d) {
  return (x << d) | (x >> (32 - d));
}

__device__ __forceinline__ void tf2x32(uint32_t k0, uint32_t k1,
                                       uint32_t x0, uint32_t x1,
                                       uint32_t& o0, uint32_t& o1) {
  uint32_t k2 = k0 ^ k1 ^ 0x1BD11BDAu;
#define TFR(r) { x0 += x1; x1 = rotl32(x1, (r)); x1 ^= x0; }
  x0 += k0; x1 += k1;
  TFR(13) TFR(15) TFR(26) TFR(6)
  x0 += k1; x1 += k2 + 1u;
  TFR(17) TFR(29) TFR(16) TFR(24)
  x0 += k2; x1 += k0 + 2u;
  TFR(13) TFR(15) TFR(26) TFR(6)
  x0 += k0; x1 += k1 + 3u;
  TFR(17) TFR(29) TFR(16) TFR(24)
  x0 += k1; x1 += k2 + 4u;
  TFR(13) TFR(15) TFR(26) TFR(6)
  x0 += k2; x1 += k0 + 5u;
#undef TFR
  o0 = x0; o1 = x1;
}

__device__ __forceinline__ float rng_u01(uint2 key, uint32_t idx) {
  uint32_t o0, o1;
  tf2x32(key.x, key.y, 0u, idx, o0, o1);
  uint32_t bits = o0 ^ o1;
  return __uint_as_float((bits >> 9) | 0x3F800000u) - 1.0f;
}

// sampling-path sigmoid: keep libm precision (bit-exact chain vs reference)
__device__ __forceinline__ float sigmoidf_(float z) {
  return 1.0f / (1.0f + expf(-z));
}
// free-energy-only softplus: fast hw transcendentals (not on sampling path)
__device__ __forceinline__ float softplus_fast(float x) {
  return fmaxf(x, 0.f) + __logf(1.f + __expf(-fabsf(x)));
}

// ------------------------------- prep kernels ------------------------------
__global__ void prep_keys(const int* __restrict__ seedp, uint2* __restrict__ keys) {
  if (threadIdx.x != 0 || blockIdx.x != 0) return;
  uint32_t seed = (uint32_t)(*seedp);
  uint2 key = make_uint2(0u, seed);
  uint2 nk, kk;
  tf2x32(key.x, key.y, 0u, 0u, nk.x, nk.y);
  tf2x32(key.x, key.y, 0u, 1u, kk.x, kk.y);
  keys[0] = kk;   // k0
  key = nk;
  for (int s = 0; s < KSTEPS; ++s) {
    uint2 t0, t1, t2, t3;
    tf2x32(key.x, key.y, 0u, 0u, t0.x, t0.y);
    tf2x32(key.x, key.y, 0u, 1u, t1.x, t1.y);
    tf2x32(key.x, key.y, 0u, 2u, t2.x, t2.y);
    tf2x32(key.x, key.y, 0u, 3u, t3.x, t3.y);
    key = t0;
    keys[1 + 3*s] = t1;  // k1
    keys[2 + 3*s] = t2;  // k2
    keys[3 + 3*s] = t3;  // k3
  }
}

__global__ void colsum_k(const float* __restrict__ W, float* __restrict__ cs) {
  int h = blockIdx.x * 256 + threadIdx.x;
  float s = 0.f;
  for (int k = 0; k < Vn; ++k) s += W[(size_t)k * Hn + h];
  cs[h] = s;
}

__global__ void bsum_k(const float* __restrict__ bvec, float* __restrict__ bs) {
  __shared__ float sb[4];
  float s = 0.f;
  for (int i = threadIdx.x; i < Vn; i += 256) s += bvec[i];
  for (int off = 32; off > 0; off >>= 1) s += __shfl_down(s, off, 64);
  int wv = threadIdx.x >> 6, ln = threadIdx.x & 63;
  if (ln == 0) sb[wv] = s;
  __syncthreads();
  if (threadIdx.x == 0) bs[0] = sb[0] + sb[1] + sb[2] + sb[3];
}

// W -> f16 (row-major) and f16 transposed, LDS-tiled for coalesced stores
__global__ __launch_bounds__(256) void cast_W(
    const float* __restrict__ W, f16* __restrict__ Wf, f16* __restrict__ WTf) {
  __shared__ f16 tile[64][65];
  const int j0 = blockIdx.x * 64, i0 = blockIdx.y * 64;
  const int tx = threadIdx.x & 63, tg = threadIdx.x >> 6;   // 4 groups of 16 rows
#pragma unroll 4
  for (int rr = 0; rr < 16; ++rr) {
    const int row = tg * 16 + rr;
    float w = W[(size_t)(i0 + row) * Hn + j0 + tx];
    f16 hw = (f16)w;
    Wf[(size_t)(i0 + row) * Hn + j0 + tx] = hw;
    tile[row][tx] = hw;
  }
  __syncthreads();
#pragma unroll 4
  for (int rr = 0; rr < 16; ++rr) {
    const int row = tg * 16 + rr;
    WTf[(size_t)(j0 + row) * Vn + i0 + tx] = tile[tx][row];
  }
}

__global__ __launch_bounds__(256) void cast_v(
    const float* __restrict__ vd, f16* __restrict__ v) {
  const int idx = blockIdx.x * 256 + threadIdx.x;   // element-group of 4
  const float4 d = ((const float4*)vd)[idx];
  f16x4 o = { (f16)d.x, (f16)d.y, (f16)d.z, (f16)d.w };
  *(f16x4*)(v + (size_t)idx * 4) = o;
}

__global__ void u0_init(const uint2* __restrict__ keys, float* __restrict__ u) {
  int b = blockIdx.x * 256 + threadIdx.x;
  float r01 = rng_u01(keys[0], (uint32_t)b);
  u[b] = (r01 < 0.5f) ? 1.f : 0.f;
}

// ------------------- GEMM: two-stage staging (Tensile-style) ----------------
// C[m][n] = sum_k A[m][k]*B[n][k]. Tile 128x128, BK=32, 32 iters, 256 thr.
// Pipeline: gload(s+3)->regs (3 rotating stages); dswrite(s+1)->LDS[(s+1)&1];
// compute(s) from LDS[s&1]; __syncthreads (lgkmcnt-only: no LDS-DMA in
// flight). Per-thread staging: 2 ids per matrix (rows t>>2 and 64+(t>>2),
// chunk t&3), phys chunk = c ^ ((row>>1)&3) (R10-verified, 0 conflicts).
template <int EPI>
__global__ __launch_bounds__(256, 2) void gemm_ts(
    const f16* __restrict__ A, const f16* __restrict__ Bm,
    float* __restrict__ outA, f16* __restrict__ outH,
    const float* __restrict__ u, const float* __restrict__ colsum,
    const float* __restrict__ cvec,
    const uint2* __restrict__ keys, int keyIdx)
{
  constexpr int N = 1024, K = 1024, BK = 32;
  __shared__ alignas(16) f16 SB[2][8192];   // per buf: A [0,4096) | B [4096,8192)

  const int t = threadIdx.x, wave = t >> 6, lane = t & 63;
  const int l15 = lane & 15, quad = lane >> 4;
  const int m0 = blockIdx.x * 128, n0 = blockIdx.y * 128;
  const int wm = (wave >> 1) * 64, wn = (wave & 1) * 64;

  // ---- staging addresses ----
  const int row0 = t >> 2;                 // 0..63
  const int c0   = t & 3;
  const int pc   = c0 ^ ((row0 >> 1) & 3); // same for row0 and row0+64
  const f16* gA0 = A  + (size_t)(m0 + row0) * K + c0 * 8;
  const f16* gA1 = gA0 + (size_t)64 * K;
  const f16* gB0 = Bm + (size_t)(n0 + row0) * K + c0 * 8;
  const f16* gB1 = gB0 + (size_t)64 * K;
  const int wA0 = row0 * 32 + pc * 8;
  const int wA1 = (row0 + 64) * 32 + pc * 8;
  const int wB0 = 4096 + wA0;
  const int wB1 = 4096 + wA1;

  uint4 rA[3][2], rB[3][2];                // 3-stage register pipeline (48 VGPR)
  auto gload = [&](int st, int s) {
    const int ko = s * BK;                 // byte offset s*64 <= 1984: immediate
    rA[st][0] = *(const uint4*)(gA0 + ko);
    rA[st][1] = *(const uint4*)(gA1 + ko);
    rB[st][0] = *(const uint4*)(gB0 + ko);
    rB[st][1] = *(const uint4*)(gB1 + ko);
  };
  auto dswrite = [&](int b, int st) {
    *(uint4*)(&SB[b][wA0]) = rA[st][0];
    *(uint4*)(&SB[b][wA1]) = rA[st][1];
    *(uint4*)(&SB[b][wB0]) = rB[st][0];
    *(uint4*)(&SB[b][wB1]) = rB[st][1];
  };

  // ---- fragment read offsets (f16 units): swz proven lane-invariant in i ----
  const int swz = (l15 >> 1) & 3;
  const int oA  = (wm + l15) * 32 + (quad ^ swz) * 8;          // + i*512 imm
  const int oB  = 4096 + (wn + l15) * 32 + (quad ^ swz) * 8;   // + i*512 imm

  gload(0, 0); gload(1, 1); gload(2, 2);
  dswrite(0, 0);                           // vmcnt(8) here, not at barrier
  __syncthreads();

  f32x4 acc[4][4] = {};
#pragma unroll
  for (int s = 0; s < 32; ++s) {
    const f16* base = SB[s & 1];
    f16x8 af[4], bf[4];
#pragma unroll
    for (int i = 0; i < 4; ++i) {
      af[i] = *(const f16x8*)(base + oA + i * 512);
      bf[i] = *(const f16x8*)(base + oB + i * 512);
    }
#pragma unroll
    for (int mt = 0; mt < 4; ++mt)
#pragma unroll
      for (int nt = 0; nt < 4; ++nt)
        acc[mt][nt] = __builtin_amdgcn_mfma_f32_16x16x32_f16(af[mt], bf[nt], acc[mt][nt], 0, 0, 0);
    if (s + 3 < 32) gload((s + 3) % 3, s + 3);     // regs freed by dswrite(s-1)
    if (s + 1 < 32) dswrite((s + 1) & 1, (s + 1) % 3);  // waits vmcnt for s+1 only
    __syncthreads();                                // lgkmcnt(0); gloads fly on
  }

  // epilogue: C/D layout col = lane&15, row = quad*4 + reg   (m89/m91)
  if constexpr (EPI == 0) {
#pragma unroll
    for (int mt = 0; mt < 4; ++mt)
#pragma unroll
      for (int r = 0; r < 4; ++r) {
        const int gm = m0 + wm + mt * 16 + quad * 4 + r;
#pragma unroll
        for (int nt = 0; nt < 4; ++nt) {
          const int gn = n0 + wn + nt * 16 + l15;
          outA[(size_t)gm * N + gn] = acc[mt][nt][r];
        }
      }
  } else {
    const uint2 key = keys[keyIdx];
#pragma unroll
    for (int mt = 0; mt < 4; ++mt)
#pragma unroll
      for (int r = 0; r < 4; ++r) {
        const int gm  = m0 + wm + mt * 16 + quad * 4 + r;
        const float ubr = u[gm];
#pragma unroll
        for (int nt = 0; nt < 4; ++nt) {
          const int gn = n0 + wn + nt * 16 + l15;
          float val = acc[mt][nt][r];
          float z = (ubr > 0.5f) ? val : (colsum[gn] - val);   // v_branch @ W
          z += cvec[gn];
          float p   = sigmoidf_(z);
          float r01 = rng_u01(key, (uint32_t)(gm * N + gn));
          outH[(size_t)gm * N + gn] = (f16)((r01 < p) ? 1.0f : 0.0f);
        }
      }
  }
}

// ---------------- fused per-row: dE -> u_new -> v_new ----------------------
__global__ __launch_bounds__(256) void row_uv(
    const float* __restrict__ a, const f16* __restrict__ v,
    const float* __restrict__ bvec, const float* __restrict__ bsum,
    const uint2* __restrict__ keys, int kU, int kV,
    f16* __restrict__ vout)
{
  __shared__ float s1[4], s2[4], s3[4];
  __shared__ float su;
  const int row = blockIdx.x;
  const int t = threadIdx.x;
  const float4 av = ((const float4*)(a + (size_t)row * Vn))[t];
  const float4 bv = ((const float4*)bvec)[t];
  const f16x4  vo = *(const f16x4*)(v + (size_t)row * Vn + t * 4);

  float asum = av.x + av.y + av.z + av.w;
  float va = (float)vo[0]*av.x + (float)vo[1]*av.y + (float)vo[2]*av.z + (float)vo[3]*av.w;
  float vb = (float)vo[0]*bv.x + (float)vo[1]*bv.y + (float)vo[2]*bv.z + (float)vo[3]*bv.w;
#pragma unroll
  for (int off = 32; off > 0; off >>= 1) {
    asum += __shfl_down(asum, off, 64);
    va   += __shfl_down(va,   off, 64);
    vb   += __shfl_down(vb,   off, 64);
  }
  const int wv = t >> 6, ln = t & 63;
  if (ln == 0) { s1[wv] = asum; s2[wv] = va; s3[wv] = vb; }
  __syncthreads();
  if (t == 0) {
    asum = s1[0] + s1[1] + s1[2] + s1[3];
    va   = s2[0] + s2[1] + s2[2] + s2[3];
    vb   = s3[0] + s3[1] + s3[2] + s3[3];
    float dE  = -bsum[0] - asum + 2.f * vb + 2.f * va;
    float p   = sigmoidf_(dE);
    float r01 = rng_u01(keys[kU], (uint32_t)row);
    su = (r01 < p) ? 1.f : 0.f;
  }
  __syncthreads();
  const float un = su;
  const uint2 kv = keys[kV];
  float az[4] = { av.x, av.y, av.z, av.w };
  float bz[4] = { bv.x, bv.y, bv.z, bv.w };
  f16x4 vn;
#pragma unroll
  for (int j = 0; j < 4; ++j) {
    float p   = sigmoidf_(az[j] + bz[j]);
    float r01 = rng_u01(kv, (uint32_t)(row * Vn + t * 4 + j));
    float x   = (r01 < p) ? 1.f : 0.f;
    vn[j] = (f16)((un > 0.5f) ? x : 1.f - x);
  }
  *(f16x4*)(vout + (size_t)row * Vn + t * 4) = vn;
}

// ------------------------------ free energy --------------------------------
__global__ __launch_bounds__(256) void fe_rows(
    const float* __restrict__ a, const f16* __restrict__ v,
    const float* __restrict__ bvec, const float* __restrict__ cvec,
    const float* __restrict__ colsum, const float* __restrict__ bsum,
    float* __restrict__ Fout)
{
  __shared__ float s1[4], s2[4], s3[4];
  const int row = blockIdx.x;
  const int t = threadIdx.x;
  const float4 m4 = ((const float4*)(a + (size_t)row * Hn))[t];
  const float4 c4 = ((const float4*)cvec)[t];
  const float4 w4 = ((const float4*)colsum)[t];
  const float4 b4 = ((const float4*)bvec)[t];
  const f16x4  v4 = *(const f16x4*)(v + (size_t)row * Vn + t * 4);

  float mm[4] = { m4.x, m4.y, m4.z, m4.w };
  float cc[4] = { c4.x, c4.y, c4.z, c4.w };
  float ww[4] = { w4.x, w4.y, w4.z, w4.w };
  float bb[4] = { b4.x, b4.y, b4.z, b4.w };
  float S1 = 0.f, S2 = 0.f, vb = 0.f;
#pragma unroll
  for (int j = 0; j < 4; ++j) {
    S1 += softplus_fast(mm[j] + cc[j]);
    S2 += softplus_fast(ww[j] - mm[j] + cc[j]);
    vb += (float)v4[j] * bb[j];
  }
#pragma unroll
  for (int off = 32; off > 0; off >>= 1) {
    S1 += __shfl_down(S1, off, 64);
    S2 += __shfl_down(S2, off, 64);
    vb += __shfl_down(vb, off, 64);
  }
  const int wv = t >> 6, ln = t & 63;
  if (ln == 0) { s1[wv] = S1; s2[wv] = S2; s3[wv] = vb; }
  __syncthreads();
  if (t == 0) {
    S1 = s1[0] + s1[1] + s1[2] + s1[3];
    S2 = s2[0] + s2[1] + s2[2] + s2[3];
    vb = s3[0] + s3[1] + s3[2] + s3[3];
    float negn = vb - S1;
    float negf = (bsum[0] - vb) - S2;
    float mx = fmaxf(negn, negf);
    Fout[row] = -(mx + logf(expf(negn - mx) + expf(negf - mx)));
  }
}

__global__ __launch_bounds__(256) void finalize_k(
    const float* __restrict__ Fd, const float* __restrict__ Fm, float* __restrict__ out)
{
  __shared__ double sb[8];
  double sd = 0.0, sm = 0.0;
  for (int i = threadIdx.x; i < Bn; i += 256) { sd += (double)Fd[i]; sm += (double)Fm[i]; }
  for (int off = 32; off > 0; off >>= 1) { sd += __shfl_down(sd, off, 64); sm += __shfl_down(sm, off, 64); }
  const int wv = threadIdx.x >> 6, ln = threadIdx.x & 63;
  if (ln == 0) { sb[wv] = sd; sb[4 + wv] = sm; }
  __syncthreads();
  if (threadIdx.x == 0) {
    sd = sb[0] + sb[1] + sb[2] + sb[3];
    sm = sb[4] + sb[5] + sb[6] + sb[7];
    out[0] = (float)((sd - sm) / (double)Bn);
  }
}

// ------------------------------ launch glue --------------------------------
extern "C" void kernel_launch(void* const* d_in, const int* in_sizes, int n_in,
                              void* d_out, int out_size, void* d_ws, size_t ws_size,
                              hipStream_t stream) {
  const float* v_data = (const float*)d_in[0];
  const float* W      = (const float*)d_in[1];
  const float* bvec   = (const float*)d_in[2];
  const float* cvec   = (const float*)d_in[3];
  const int*   seedp  = (const int*)d_in[4];
  float* out = (float*)d_out;

  char* ws = (char*)d_ws;
  size_t off = 0;
  auto alloc = [&](size_t bytes) -> void* {
    void* p = ws + off;
    off += (bytes + 255) & ~(size_t)255;
    return p;
  };
  f16*   v    = (f16*)alloc((size_t)Bn * Vn * 2);     // 16 MB
  f16*   h    = (f16*)alloc((size_t)Bn * Hn * 2);     // 16 MB
  float* a    = (float*)alloc((size_t)Bn * Vn * 4);   // 32 MB
  f16*   Wf   = (f16*)alloc((size_t)Vn * Hn * 2);     // 2 MB  [V][H]
  f16*   WTf  = (f16*)alloc((size_t)Vn * Hn * 2);     // 2 MB  [H][V]
  float* colsum = (float*)alloc(Hn * 4);
  float* bsum   = (float*)alloc(256);
  uint2* keys   = (uint2*)alloc(64 * sizeof(uint2));
  float* u      = (float*)alloc(Bn * 4);
  float* Fd     = (float*)alloc(Bn * 4);
  float* Fm     = (float*)alloc(Bn * 4);
  (void)ws_size; (void)in_sizes; (void)n_in; (void)out_size;

  prep_keys<<<1, 64, 0, stream>>>(seedp, keys);
  colsum_k<<<Hn / 256, 256, 0, stream>>>(W, colsum);
  bsum_k<<<1, 256, 0, stream>>>(bvec, bsum);
  cast_W<<<dim3(Hn / 64, Vn / 64), 256, 0, stream>>>(W, Wf, WTf);
  cast_v<<<(Bn * Vn / 4) / 256, 256, 0, stream>>>(v_data, v);
  u0_init<<<Bn / 256, 256, 0, stream>>>(keys, u);

  dim3 gg(Bn / 128, Hn / 128);   // 64 x 8 = 512 blocks, 2/CU

  // F(v_data): a = v_data @ W
  gemm_ts<0><<<gg, 256, 0, stream>>>(v, WTf, a,
                                     nullptr, nullptr, nullptr, nullptr, nullptr, 0);
  fe_rows<<<Bn, 256, 0, stream>>>(a, v, bvec, cvec, colsum, bsum, Fd);

  for (int s = 0; s < KSTEPS; ++s) {
    // h = Bern(sigmoid(v_branch @ W + c)), fused threefry epilogue
    gemm_ts<1><<<gg, 256, 0, stream>>>(v, WTf, nullptr,
                                       h, u, colsum, cvec, keys, 1 + 3 * s);
    // a = h @ W^T
    gemm_ts<0><<<gg, 256, 0, stream>>>(h, Wf, a,
                                       nullptr, nullptr, nullptr, nullptr, nullptr, 0);
    // dE -> u_new -> v_new (fused)
    row_uv<<<Bn, 256, 0, stream>>>(a, v, bvec, bsum, keys, 2 + 3 * s, 3 + 3 * s, v);
  }

  // F(v_model)
  gemm_ts<0><<<gg, 256, 0, stream>>>(v, WTf, a,
                                     nullptr, nullptr, nullptr, nullptr, nullptr, 0);
  fe_rows<<<Bn, 256, 0, stream>>>(a, v, bvec, cvec, colsum, bsum, Fm);

  finalize_k<<<1, 256, 0, stream>>>(Fd, Fm, out);
}

// Round 12
// 1080.100 us; speedup vs baseline: 2.1570x; 2.1570x over previous
//
#include <hip/hip_runtime.h>
#include <hip/hip_bf16.h>
#include <stdint.h>
#include <math.h>

// ---------------------------------------------------------------------------
// SymmetricRBM: CD loss, 10-step Gibbs, JAX-threefry-exact RNG.
// B=8192, V=H=1024. R11->R12:
//  1) gemm: 64x64xBK64 2-barrier tile, launch_bounds(256,8) -> grid 2048 =
//     exactly 8 blocks/CU = 32 waves/CU (FULL occupancy; R5 showed occupancy
//     is the only lever that moved the latency-bound K-loop: 57->48 us).
//  2) intermediate a stored f16 (halves 64 MB/step of a-traffic).
//  3) fast sampling: accept iff r01 + r01*__expf(-z) < 1  (no libm, no div).
//     First non-bit-exact round; measured f16-W evidence bounds chain-
//     decorrelation effects well under the 0.0913 threshold.
// Threefry key schedule unchanged (JAX-exact draws).
// ---------------------------------------------------------------------------

static constexpr int Bn = 8192;
static constexpr int Vn = 1024;
static constexpr int Hn = 1024;
static constexpr int KSTEPS = 10;

typedef _Float16 f16;
typedef f16   f16x4 __attribute__((ext_vector_type(4)));
typedef f16   f16x8 __attribute__((ext_vector_type(8)));
typedef float f32x4 __attribute__((ext_vector_type(4)));

#define GLOBAL_LOAD_LDS16(g, l)                                              \
  __builtin_amdgcn_global_load_lds(                                          \
      (const __attribute__((address_space(1))) uint32_t*)(g),                \
      (__attribute__((address_space(3))) uint32_t*)(l), 16, 0, 0)

// ------------------------- Threefry-2x32 (JAX-exact) -----------------------
__device__ __forceinline__ uint32_t rotl32(uint32_t x, int d) {
  return (x << d) | (x >> (32 - d));
}

__device__ __forceinline__ void tf2x32(uint32_t k0, uint32_t k1,
                                       uint32_t x0, uint32_t x1,
                                       uint32_t& o0, uint32_t& o1) {
  uint32_t k2 = k0 ^ k1 ^ 0x1BD11BDAu;
#define TFR(r) { x0 += x1; x1 = rotl32(x1, (r)); x1 ^= x0; }
  x0 += k0; x1 += k1;
  TFR(13) TFR(15) TFR(26) TFR(6)
  x0 += k1; x1 += k2 + 1u;
  TFR(17) TFR(29) TFR(16) TFR(24)
  x0 += k2; x1 += k0 + 2u;
  TFR(13) TFR(15) TFR(26) TFR(6)
  x0 += k0; x1 += k1 + 3u;
  TFR(17) TFR(29) TFR(16) TFR(24)
  x0 += k1; x1 += k2 + 4u;
  TFR(13) TFR(15) TFR(26) TFR(6)
  x0 += k2; x1 += k0 + 5u;
#undef TFR
  o0 = x0; o1 = x1;
}

__device__ __forceinline__ float rng_u01(uint2 key, uint32_t idx) {
  uint32_t o0, o1;
  tf2x32(key.x, key.y, 0u, idx, o0, o1);
  uint32_t bits = o0 ^ o1;
  return __uint_as_float((bits >> 9) | 0x3F800000u) - 1.0f;
}

// fast Bernoulli accept: r01 < sigmoid(z)  <=>  r01*(1+exp(-z)) < 1
// (exp->+inf => reject, exp->0 => accept; monotone, NaN-free)
__device__ __forceinline__ float bern_fast(float z, float r01) {
  float e = __expf(-z);
  return (__builtin_fmaf(r01, e, r01) < 1.0f) ? 1.f : 0.f;
}
// free-energy softplus: fast hw transcendentals
__device__ __forceinline__ float softplus_fast(float x) {
  return fmaxf(x, 0.f) + __logf(1.f + __expf(-fabsf(x)));
}

// ------------------------------- prep kernels ------------------------------
__global__ void prep_keys(const int* __restrict__ seedp, uint2* __restrict__ keys) {
  if (threadIdx.x != 0 || blockIdx.x != 0) return;
  uint32_t seed = (uint32_t)(*seedp);
  uint2 key = make_uint2(0u, seed);
  uint2 nk, kk;
  tf2x32(key.x, key.y, 0u, 0u, nk.x, nk.y);
  tf2x32(key.x, key.y, 0u, 1u, kk.x, kk.y);
  keys[0] = kk;   // k0
  key = nk;
  for (int s = 0; s < KSTEPS; ++s) {
    uint2 t0, t1, t2, t3;
    tf2x32(key.x, key.y, 0u, 0u, t0.x, t0.y);
    tf2x32(key.x, key.y, 0u, 1u, t1.x, t1.y);
    tf2x32(key.x, key.y, 0u, 2u, t2.x, t2.y);
    tf2x32(key.x, key.y, 0u, 3u, t3.x, t3.y);
    key = t0;
    keys[1 + 3*s] = t1;  // k1
    keys[2 + 3*s] = t2;  // k2
    keys[3 + 3*s] = t3;  // k3
  }
}

__global__ void colsum_k(const float* __restrict__ W, float* __restrict__ cs) {
  int h = blockIdx.x * 256 + threadIdx.x;
  float s = 0.f;
  for (int k = 0; k < Vn; ++k) s += W[(size_t)k * Hn + h];
  cs[h] = s;
}

__global__ void bsum_k(const float* __restrict__ bvec, float* __restrict__ bs) {
  __shared__ float sb[4];
  float s = 0.f;
  for (int i = threadIdx.x; i < Vn; i += 256) s += bvec[i];
  for (int off = 32; off > 0; off >>= 1) s += __shfl_down(s, off, 64);
  int wv = threadIdx.x >> 6, ln = threadIdx.x & 63;
  if (ln == 0) sb[wv] = s;
  __syncthreads();
  if (threadIdx.x == 0) bs[0] = sb[0] + sb[1] + sb[2] + sb[3];
}

// W -> f16 (row-major) and f16 transposed, LDS-tiled for coalesced stores
__global__ __launch_bounds__(256) void cast_W(
    const float* __restrict__ W, f16* __restrict__ Wf, f16* __restrict__ WTf) {
  __shared__ f16 tile[64][65];
  const int j0 = blockIdx.x * 64, i0 = blockIdx.y * 64;
  const int tx = threadIdx.x & 63, tg = threadIdx.x >> 6;   // 4 groups of 16 rows
#pragma unroll 4
  for (int rr = 0; rr < 16; ++rr) {
    const int row = tg * 16 + rr;
    float w = W[(size_t)(i0 + row) * Hn + j0 + tx];
    f16 hw = (f16)w;
    Wf[(size_t)(i0 + row) * Hn + j0 + tx] = hw;
    tile[row][tx] = hw;
  }
  __syncthreads();
#pragma unroll 4
  for (int rr = 0; rr < 16; ++rr) {
    const int row = tg * 16 + rr;
    WTf[(size_t)(j0 + row) * Vn + i0 + tx] = tile[tx][row];
  }
}

__global__ __launch_bounds__(256) void cast_v(
    const float* __restrict__ vd, f16* __restrict__ v) {
  const int idx = blockIdx.x * 256 + threadIdx.x;   // element-group of 4
  const float4 d = ((const float4*)vd)[idx];
  f16x4 o = { (f16)d.x, (f16)d.y, (f16)d.z, (f16)d.w };
  *(f16x4*)(v + (size_t)idx * 4) = o;
}

__global__ void u0_init(const uint2* __restrict__ keys, float* __restrict__ u) {
  int b = blockIdx.x * 256 + threadIdx.x;
  float r01 = rng_u01(keys[0], (uint32_t)b);
  u[b] = (r01 < 0.5f) ? 1.f : 0.f;
}

// ------------------------- GEMM: 64x64 max-occupancy ------------------------
// C[m][n] = sum_k A[m][k]*B[n][k]. BK=64 (16 iters), 256 thr (4 waves, 2x2,
// wave tile 32x32). LDS 16 KB/block; grid 2048 = 8 blocks/CU (full 32 waves).
// Swizzle: 16B chunk c of row r at phys c^(r&7); staging line-coalesced,
// fragment ds_read_b128 2 lanes/bank (conflict-free).
// EPI 0: store f16 C. EPI 1: h = Bern(sigmoid(branch(C)+c)) fused (fast path).
template <int EPI>
__global__ __launch_bounds__(256, 8) void gemm_s(
    const f16* __restrict__ A, const f16* __restrict__ Bm,
    f16* __restrict__ outA, f16* __restrict__ outH,
    const float* __restrict__ u, const float* __restrict__ colsum,
    const float* __restrict__ cvec,
    const uint2* __restrict__ keys, int keyIdx)
{
  constexpr int N = 1024, K = 1024, BK = 64;
  __shared__ alignas(16) f16 As[64 * BK];   // 8 KB
  __shared__ alignas(16) f16 Bs[64 * BK];   // 8 KB

  const int t = threadIdx.x, wave = t >> 6, lane = t & 63;
  const int l15 = lane & 15, quad = lane >> 4;
  const int m0 = blockIdx.x * 64, n0 = blockIdx.y * 64;
  const int wm = (wave >> 1) * 32, wn = (wave & 1) * 32;

  // staging: instr i covers rows wave*16 + i*8 + (lane>>3); lane fetches
  // global chunk (lane&7) ^ (lane>>3)  [row&7 = lane>>3]
  const int rbase = lane >> 3;                 // 0..7
  const int gch   = (lane & 7) ^ rbase;
  const f16* gA = A  + (size_t)(m0 + wave * 16 + rbase) * K + gch * 8;
  const f16* gB = Bm + (size_t)(n0 + wave * 16 + rbase) * K + gch * 8;
  f16* lA = As + wave * 16 * BK;               // +i*8*BK per instr
  f16* lB = Bs + wave * 16 * BK;

  // fragment reads: row = w? + i*16 + l15 (≡ l15 mod 8); chunk (kc*4+quad)^swz
  const int swz = l15 & 7;
  const int oA  = (wm + l15) * BK;             // + ((kc*4+quad)^swz)*8 + i*16*BK
  const int oB  = (wn + l15) * BK;

  f32x4 acc[2][2] = {};

  for (int k0 = 0; k0 < K; k0 += BK) {
    GLOBAL_LOAD_LDS16(gA + k0,         lA);
    GLOBAL_LOAD_LDS16(gA + k0 + 8 * K, lA + 8 * BK);
    GLOBAL_LOAD_LDS16(gB + k0,         lB);
    GLOBAL_LOAD_LDS16(gB + k0 + 8 * K, lB + 8 * BK);
    __syncthreads();

#pragma unroll
    for (int kc = 0; kc < 2; ++kc) {
      const int fc = ((kc * 4 + quad) ^ swz) * 8;
      f16x8 af[2], bf[2];
#pragma unroll
      for (int i = 0; i < 2; ++i) {
        af[i] = *(const f16x8*)(&As[oA + i * 16 * BK + fc]);
        bf[i] = *(const f16x8*)(&Bs[oB + i * 16 * BK + fc]);
      }
#pragma unroll
      for (int mt = 0; mt < 2; ++mt)
#pragma unroll
        for (int nt = 0; nt < 2; ++nt)
          acc[mt][nt] = __builtin_amdgcn_mfma_f32_16x16x32_f16(af[mt], bf[nt], acc[mt][nt], 0, 0, 0);
    }
    __syncthreads();
  }

  // epilogue: C/D layout col = lane&15, row = quad*4 + reg   (m89/m91)
  if constexpr (EPI == 0) {
#pragma unroll
    for (int mt = 0; mt < 2; ++mt)
#pragma unroll
      for (int r = 0; r < 4; ++r) {
        const int gm = m0 + wm + mt * 16 + quad * 4 + r;
#pragma unroll
        for (int nt = 0; nt < 2; ++nt) {
          const int gn = n0 + wn + nt * 16 + l15;
          outA[(size_t)gm * N + gn] = (f16)acc[mt][nt][r];
        }
      }
  } else {
    const uint2 key = keys[keyIdx];
#pragma unroll
    for (int mt = 0; mt < 2; ++mt)
#pragma unroll
      for (int r = 0; r < 4; ++r) {
        const int gm  = m0 + wm + mt * 16 + quad * 4 + r;
        const float ubr = u[gm];
#pragma unroll
        for (int nt = 0; nt < 2; ++nt) {
          const int gn = n0 + wn + nt * 16 + l15;
          float val = acc[mt][nt][r];
          float z = (ubr > 0.5f) ? val : (colsum[gn] - val);   // v_branch @ W
          z += cvec[gn];
          float r01 = rng_u01(key, (uint32_t)(gm * N + gn));
          outH[(size_t)gm * N + gn] = (f16)bern_fast(z, r01);
        }
      }
  }
}

// ---------------- fused per-row: dE -> u_new -> v_new ----------------------
__global__ __launch_bounds__(256) void row_uv(
    const f16* __restrict__ a, const f16* __restrict__ v,
    const float* __restrict__ bvec, const float* __restrict__ bsum,
    const uint2* __restrict__ keys, int kU, int kV,
    f16* __restrict__ vout)
{
  __shared__ float s1[4], s2[4], s3[4];
  __shared__ float su;
  const int row = blockIdx.x;
  const int t = threadIdx.x;
  const f16x4  a4 = *(const f16x4*)(a + (size_t)row * Vn + t * 4);
  const float4 bv = ((const float4*)bvec)[t];
  const f16x4  vo = *(const f16x4*)(v + (size_t)row * Vn + t * 4);
  float az[4] = { (float)a4[0], (float)a4[1], (float)a4[2], (float)a4[3] };
  float bz[4] = { bv.x, bv.y, bv.z, bv.w };

  float asum = az[0] + az[1] + az[2] + az[3];
  float va = (float)vo[0]*az[0] + (float)vo[1]*az[1] + (float)vo[2]*az[2] + (float)vo[3]*az[3];
  float vb = (float)vo[0]*bz[0] + (float)vo[1]*bz[1] + (float)vo[2]*bz[2] + (float)vo[3]*bz[3];
#pragma unroll
  for (int off = 32; off > 0; off >>= 1) {
    asum += __shfl_down(asum, off, 64);
    va   += __shfl_down(va,   off, 64);
    vb   += __shfl_down(vb,   off, 64);
  }
  const int wv = t >> 6, ln = t & 63;
  if (ln == 0) { s1[wv] = asum; s2[wv] = va; s3[wv] = vb; }
  __syncthreads();
  if (t == 0) {
    asum = s1[0] + s1[1] + s1[2] + s1[3];
    va   = s2[0] + s2[1] + s2[2] + s2[3];
    vb   = s3[0] + s3[1] + s3[2] + s3[3];
    float dE  = -bsum[0] - asum + 2.f * vb + 2.f * va;
    float r01 = rng_u01(keys[kU], (uint32_t)row);
    su = bern_fast(dE, r01);
  }
  __syncthreads();
  const float un = su;
  const uint2 kv = keys[kV];
  f16x4 vn;
#pragma unroll
  for (int j = 0; j < 4; ++j) {
    float r01 = rng_u01(kv, (uint32_t)(row * Vn + t * 4 + j));
    float x   = bern_fast(az[j] + bz[j], r01);
    vn[j] = (f16)((un > 0.5f) ? x : 1.f - x);
  }
  *(f16x4*)(vout + (size_t)row * Vn + t * 4) = vn;
}

// ------------------------------ free energy --------------------------------
__global__ __launch_bounds__(256) void fe_rows(
    const f16* __restrict__ a, const f16* __restrict__ v,
    const float* __restrict__ bvec, const float* __restrict__ cvec,
    const float* __restrict__ colsum, const float* __restrict__ bsum,
    float* __restrict__ Fout)
{
  __shared__ float s1[4], s2[4], s3[4];
  const int row = blockIdx.x;
  const int t = threadIdx.x;
  const f16x4  a4 = *(const f16x4*)(a + (size_t)row * Hn + t * 4);
  const float4 c4 = ((const float4*)cvec)[t];
  const float4 w4 = ((const float4*)colsum)[t];
  const float4 b4 = ((const float4*)bvec)[t];
  const f16x4  v4 = *(const f16x4*)(v + (size_t)row * Vn + t * 4);

  float mm[4] = { (float)a4[0], (float)a4[1], (float)a4[2], (float)a4[3] };
  float cc[4] = { c4.x, c4.y, c4.z, c4.w };
  float ww[4] = { w4.x, w4.y, w4.z, w4.w };
  float bb[4] = { b4.x, b4.y, b4.z, b4.w };
  float S1 = 0.f, S2 = 0.f, vb = 0.f;
#pragma unroll
  for (int j = 0; j < 4; ++j) {
    S1 += softplus_fast(mm[j] + cc[j]);
    S2 += softplus_fast(ww[j] - mm[j] + cc[j]);
    vb += (float)v4[j] * bb[j];
  }
#pragma unroll
  for (int off = 32; off > 0; off >>= 1) {
    S1 += __shfl_down(S1, off, 64);
    S2 += __shfl_down(S2, off, 64);
    vb += __shfl_down(vb, off, 64);
  }
  const int wv = t >> 6, ln = t & 63;
  if (ln == 0) { s1[wv] = S1; s2[wv] = S2; s3[wv] = vb; }
  __syncthreads();
  if (t == 0) {
    S1 = s1[0] + s1[1] + s1[2] + s1[3];
    S2 = s2[0] + s2[1] + s2[2] + s2[3];
    vb = s3[0] + s3[1] + s3[2] + s3[3];
    float negn = vb - S1;
    float negf = (bsum[0] - vb) - S2;
    float mx = fmaxf(negn, negf);
    Fout[row] = -(mx + logf(expf(negn - mx) + expf(negf - mx)));
  }
}

__global__ __launch_bounds__(256) void finalize_k(
    const float* __restrict__ Fd, const float* __restrict__ Fm, float* __restrict__ out)
{
  __shared__ double sb[8];
  double sd = 0.0, sm = 0.0;
  for (int i = threadIdx.x; i < Bn; i += 256) { sd += (double)Fd[i]; sm += (double)Fm[i]; }
  for (int off = 32; off > 0; off >>= 1) { sd += __shfl_down(sd, off, 64); sm += __shfl_down(sm, off, 64); }
  const int wv = threadIdx.x >> 6, ln = threadIdx.x & 63;
  if (ln == 0) { sb[wv] = sd; sb[4 + wv] = sm; }
  __syncthreads();
  if (threadIdx.x == 0) {
    sd = sb[0] + sb[1] + sb[2] + sb[3];
    sm = sb[4] + sb[5] + sb[6] + sb[7];
    out[0] = (float)((sd - sm) / (double)Bn);
  }
}

// ------------------------------ launch glue --------------------------------
extern "C" void kernel_launch(void* const* d_in, const int* in_sizes, int n_in,
                              void* d_out, int out_size, void* d_ws, size_t ws_size,
                              hipStream_t stream) {
  const float* v_data = (const float*)d_in[0];
  const float* W      = (const float*)d_in[1];
  const float* bvec   = (const float*)d_in[2];
  const float* cvec   = (const float*)d_in[3];
  const int*   seedp  = (const int*)d_in[4];
  float* out = (float*)d_out;

  char* ws = (char*)d_ws;
  size_t off = 0;
  auto alloc = [&](size_t bytes) -> void* {
    void* p = ws + off;
    off += (bytes + 255) & ~(size_t)255;
    return p;
  };
  f16*   v    = (f16*)alloc((size_t)Bn * Vn * 2);     // 16 MB
  f16*   h    = (f16*)alloc((size_t)Bn * Hn * 2);     // 16 MB
  f16*   a    = (f16*)alloc((size_t)Bn * Vn * 2);     // 16 MB (was fp32)
  f16*   Wf   = (f16*)alloc((size_t)Vn * Hn * 2);     // 2 MB  [V][H]
  f16*   WTf  = (f16*)alloc((size_t)Vn * Hn * 2);     // 2 MB  [H][V]
  float* colsum = (float*)alloc(Hn * 4);
  float* bsum   = (float*)alloc(256);
  uint2* keys   = (uint2*)alloc(64 * sizeof(uint2));
  float* u      = (float*)alloc(Bn * 4);
  float* Fd     = (float*)alloc(Bn * 4);
  float* Fm     = (float*)alloc(Bn * 4);
  (void)ws_size; (void)in_sizes; (void)n_in; (void)out_size;

  prep_keys<<<1, 64, 0, stream>>>(seedp, keys);
  colsum_k<<<Hn / 256, 256, 0, stream>>>(W, colsum);
  bsum_k<<<1, 256, 0, stream>>>(bvec, bsum);
  cast_W<<<dim3(Hn / 64, Vn / 64), 256, 0, stream>>>(W, Wf, WTf);
  cast_v<<<(Bn * Vn / 4) / 256, 256, 0, stream>>>(v_data, v);
  u0_init<<<Bn / 256, 256, 0, stream>>>(keys, u);

  dim3 gg(Bn / 64, Hn / 64);   // 128 x 16 = 2048 blocks = 8/CU

  // F(v_data): a = v_data @ W
  gemm_s<0><<<gg, 256, 0, stream>>>(v, WTf, a,
                                    nullptr, nullptr, nullptr, nullptr, nullptr, 0);
  fe_rows<<<Bn, 256, 0, stream>>>(a, v, bvec, cvec, colsum, bsum, Fd);

  for (int s = 0; s < KSTEPS; ++s) {
    // h = Bern(sigmoid(v_branch @ W + c)), fused threefry epilogue
    gemm_s<1><<<gg, 256, 0, stream>>>(v, WTf, nullptr,
                                      h, u, colsum, cvec, keys, 1 + 3 * s);
    // a = h @ W^T
    gemm_s<0><<<gg, 256, 0, stream>>>(h, Wf, a,
                                      nullptr, nullptr, nullptr, nullptr, nullptr, 0);
    // dE -> u_new -> v_new (fused)
    row_uv<<<Bn, 256, 0, stream>>>(a, v, bvec, bsum, keys, 2 + 3 * s, 3 + 3 * s, v);
  }

  // F(v_model)
  gemm_s<0><<<gg, 256, 0, stream>>>(v, WTf, a,
                                    nullptr, nullptr, nullptr, nullptr, nullptr, 0);
  fe_rows<<<Bn, 256, 0, stream>>>(a, v, bvec, cvec, colsum, bsum, Fm);

  finalize_k<<<1, 256, 0, stream>>>(Fd, Fm, out);
}

// Round 13
// 1042.139 us; speedup vs baseline: 2.2356x; 1.0364x over previous
//
#include <hip/hip_runtime.h>
#include <hip/hip_bf16.h>
#include <stdint.h>
#include <math.h>

// ---------------------------------------------------------------------------
// SymmetricRBM: CD loss, 10-step Gibbs, JAX-threefry-exact RNG.
// B=8192, V=H=1024. R12->R13:
//  1) colsum: 4-block strided loop (45 us on 4 CUs!) -> two-stage deterministic
//     reduction over 64 row-stripes (~2 us).
//  2) F(v_data) gemm fused into step-0's sampling gemm (EPI=2 writes raw
//     a = v@W AND samples h): 22 -> 21 gemm dispatches.
// gemm_s itself unchanged from R12 (64x64xBK64, 8 blocks/CU, 43 us, the
// proven HIP-source sweet spot after 7 failed pipelining structures).
// ---------------------------------------------------------------------------

static constexpr int Bn = 8192;
static constexpr int Vn = 1024;
static constexpr int Hn = 1024;
static constexpr int KSTEPS = 10;

typedef _Float16 f16;
typedef f16   f16x4 __attribute__((ext_vector_type(4)));
typedef f16   f16x8 __attribute__((ext_vector_type(8)));
typedef float f32x4 __attribute__((ext_vector_type(4)));

#define GLOBAL_LOAD_LDS16(g, l)                                              \
  __builtin_amdgcn_global_load_lds(                                          \
      (const __attribute__((address_space(1))) uint32_t*)(g),                \
      (__attribute__((address_space(3))) uint32_t*)(l), 16, 0, 0)

// ------------------------- Threefry-2x32 (JAX-exact) -----------------------
__device__ __forceinline__ uint32_t rotl32(uint32_t x, int d) {
  return (x << d) | (x >> (32 - d));
}

__device__ __forceinline__ void tf2x32(uint32_t k0, uint32_t k1,
                                       uint32_t x0, uint32_t x1,
                                       uint32_t& o0, uint32_t& o1) {
  uint32_t k2 = k0 ^ k1 ^ 0x1BD11BDAu;
#define TFR(r) { x0 += x1; x1 = rotl32(x1, (r)); x1 ^= x0; }
  x0 += k0; x1 += k1;
  TFR(13) TFR(15) TFR(26) TFR(6)
  x0 += k1; x1 += k2 + 1u;
  TFR(17) TFR(29) TFR(16) TFR(24)
  x0 += k2; x1 += k0 + 2u;
  TFR(13) TFR(15) TFR(26) TFR(6)
  x0 += k0; x1 += k1 + 3u;
  TFR(17) TFR(29) TFR(16) TFR(24)
  x0 += k1; x1 += k2 + 4u;
  TFR(13) TFR(15) TFR(26) TFR(6)
  x0 += k2; x1 += k0 + 5u;
#undef TFR
  o0 = x0; o1 = x1;
}

__device__ __forceinline__ float rng_u01(uint2 key, uint32_t idx) {
  uint32_t o0, o1;
  tf2x32(key.x, key.y, 0u, idx, o0, o1);
  uint32_t bits = o0 ^ o1;
  return __uint_as_float((bits >> 9) | 0x3F800000u) - 1.0f;
}

// fast Bernoulli accept: r01 < sigmoid(z)  <=>  r01*(1+exp(-z)) < 1
__device__ __forceinline__ float bern_fast(float z, float r01) {
  float e = __expf(-z);
  return (__builtin_fmaf(r01, e, r01) < 1.0f) ? 1.f : 0.f;
}
// free-energy softplus: fast hw transcendentals
__device__ __forceinline__ float softplus_fast(float x) {
  return fmaxf(x, 0.f) + __logf(1.f + __expf(-fabsf(x)));
}

// ------------------------------- prep kernels ------------------------------
__global__ void prep_keys(const int* __restrict__ seedp, uint2* __restrict__ keys) {
  if (threadIdx.x != 0 || blockIdx.x != 0) return;
  uint32_t seed = (uint32_t)(*seedp);
  uint2 key = make_uint2(0u, seed);
  uint2 nk, kk;
  tf2x32(key.x, key.y, 0u, 0u, nk.x, nk.y);
  tf2x32(key.x, key.y, 0u, 1u, kk.x, kk.y);
  keys[0] = kk;   // k0
  key = nk;
  for (int s = 0; s < KSTEPS; ++s) {
    uint2 t0, t1, t2, t3;
    tf2x32(key.x, key.y, 0u, 0u, t0.x, t0.y);
    tf2x32(key.x, key.y, 0u, 1u, t1.x, t1.y);
    tf2x32(key.x, key.y, 0u, 2u, t2.x, t2.y);
    tf2x32(key.x, key.y, 0u, 3u, t3.x, t3.y);
    key = t0;
    keys[1 + 3*s] = t1;  // k1
    keys[2 + 3*s] = t2;  // k2
    keys[3 + 3*s] = t3;  // k3
  }
}

// colsum stage 1: block (bx) sums rows bx*16..bx*16+15 over all 1024 cols.
// 64 blocks x 256 thr; thread t covers cols {t, t+256, t+512, t+768}; reads
// coalesced row-major. Deterministic (fixed order).
__global__ __launch_bounds__(256) void colsum_part(
    const float* __restrict__ W, float* __restrict__ part) {
  const int bx = blockIdx.x, t = threadIdx.x;
  float s0 = 0.f, s1 = 0.f, s2 = 0.f, s3 = 0.f;
#pragma unroll
  for (int r = 0; r < 16; ++r) {
    const float* row = W + (size_t)(bx * 16 + r) * Hn;
    s0 += row[t];
    s1 += row[t + 256];
    s2 += row[t + 512];
    s3 += row[t + 768];
  }
  float* p = part + (size_t)bx * Hn;
  p[t] = s0; p[t + 256] = s1; p[t + 512] = s2; p[t + 768] = s3;
}

// colsum stage 2: 4 blocks x 256 thr; col = b*256+t; sum 64 partials.
__global__ __launch_bounds__(256) void colsum_red(
    const float* __restrict__ part, float* __restrict__ cs) {
  const int col = blockIdx.x * 256 + threadIdx.x;
  float s = 0.f;
#pragma unroll
  for (int k = 0; k < 64; ++k) s += part[(size_t)k * Hn + col];
  cs[col] = s;
}

__global__ void bsum_k(const float* __restrict__ bvec, float* __restrict__ bs) {
  __shared__ float sb[4];
  float s = 0.f;
  for (int i = threadIdx.x; i < Vn; i += 256) s += bvec[i];
  for (int off = 32; off > 0; off >>= 1) s += __shfl_down(s, off, 64);
  int wv = threadIdx.x >> 6, ln = threadIdx.x & 63;
  if (ln == 0) sb[wv] = s;
  __syncthreads();
  if (threadIdx.x == 0) bs[0] = sb[0] + sb[1] + sb[2] + sb[3];
}

// W -> f16 (row-major) and f16 transposed, LDS-tiled for coalesced stores
__global__ __launch_bounds__(256) void cast_W(
    const float* __restrict__ W, f16* __restrict__ Wf, f16* __restrict__ WTf) {
  __shared__ f16 tile[64][65];
  const int j0 = blockIdx.x * 64, i0 = blockIdx.y * 64;
  const int tx = threadIdx.x & 63, tg = threadIdx.x >> 6;   // 4 groups of 16 rows
#pragma unroll 4
  for (int rr = 0; rr < 16; ++rr) {
    const int row = tg * 16 + rr;
    float w = W[(size_t)(i0 + row) * Hn + j0 + tx];
    f16 hw = (f16)w;
    Wf[(size_t)(i0 + row) * Hn + j0 + tx] = hw;
    tile[row][tx] = hw;
  }
  __syncthreads();
#pragma unroll 4
  for (int rr = 0; rr < 16; ++rr) {
    const int row = tg * 16 + rr;
    WTf[(size_t)(j0 + row) * Vn + i0 + tx] = tile[tx][row];
  }
}

__global__ __launch_bounds__(256) void cast_v(
    const float* __restrict__ vd, f16* __restrict__ v) {
  const int idx = blockIdx.x * 256 + threadIdx.x;   // element-group of 4
  const float4 d = ((const float4*)vd)[idx];
  f16x4 o = { (f16)d.x, (f16)d.y, (f16)d.z, (f16)d.w };
  *(f16x4*)(v + (size_t)idx * 4) = o;
}

__global__ void u0_init(const uint2* __restrict__ keys, float* __restrict__ u) {
  int b = blockIdx.x * 256 + threadIdx.x;
  float r01 = rng_u01(keys[0], (uint32_t)b);
  u[b] = (r01 < 0.5f) ? 1.f : 0.f;
}

// ------------------------- GEMM: 64x64 max-occupancy ------------------------
// C[m][n] = sum_k A[m][k]*B[n][k]. BK=64 (16 iters), 256 thr (4 waves, 2x2,
// wave tile 32x32). LDS 16 KB/block; grid 2048 = 8 blocks/CU (full 32 waves).
// Swizzle: 16B chunk c of row r at phys c^(r&7); conflict-free (R12: 0).
// EPI 0: store f16 C.  EPI 1: h = Bern fused.  EPI 2: both (step-0 fusion).
template <int EPI>
__global__ __launch_bounds__(256, 8) void gemm_s(
    const f16* __restrict__ A, const f16* __restrict__ Bm,
    f16* __restrict__ outA, f16* __restrict__ outH,
    const float* __restrict__ u, const float* __restrict__ colsum,
    const float* __restrict__ cvec,
    const uint2* __restrict__ keys, int keyIdx)
{
  constexpr int N = 1024, K = 1024, BK = 64;
  __shared__ alignas(16) f16 As[64 * BK];   // 8 KB
  __shared__ alignas(16) f16 Bs[64 * BK];   // 8 KB

  const int t = threadIdx.x, wave = t >> 6, lane = t & 63;
  const int l15 = lane & 15, quad = lane >> 4;
  const int m0 = blockIdx.x * 64, n0 = blockIdx.y * 64;
  const int wm = (wave >> 1) * 32, wn = (wave & 1) * 32;

  const int rbase = lane >> 3;                 // 0..7
  const int gch   = (lane & 7) ^ rbase;
  const f16* gA = A  + (size_t)(m0 + wave * 16 + rbase) * K + gch * 8;
  const f16* gB = Bm + (size_t)(n0 + wave * 16 + rbase) * K + gch * 8;
  f16* lA = As + wave * 16 * BK;
  f16* lB = Bs + wave * 16 * BK;

  const int swz = l15 & 7;
  const int oA  = (wm + l15) * BK;
  const int oB  = (wn + l15) * BK;

  f32x4 acc[2][2] = {};

  for (int k0 = 0; k0 < K; k0 += BK) {
    GLOBAL_LOAD_LDS16(gA + k0,         lA);
    GLOBAL_LOAD_LDS16(gA + k0 + 8 * K, lA + 8 * BK);
    GLOBAL_LOAD_LDS16(gB + k0,         lB);
    GLOBAL_LOAD_LDS16(gB + k0 + 8 * K, lB + 8 * BK);
    __syncthreads();

#pragma unroll
    for (int kc = 0; kc < 2; ++kc) {
      const int fc = ((kc * 4 + quad) ^ swz) * 8;
      f16x8 af[2], bf[2];
#pragma unroll
      for (int i = 0; i < 2; ++i) {
        af[i] = *(const f16x8*)(&As[oA + i * 16 * BK + fc]);
        bf[i] = *(const f16x8*)(&Bs[oB + i * 16 * BK + fc]);
      }
#pragma unroll
      for (int mt = 0; mt < 2; ++mt)
#pragma unroll
        for (int nt = 0; nt < 2; ++nt)
          acc[mt][nt] = __builtin_amdgcn_mfma_f32_16x16x32_f16(af[mt], bf[nt], acc[mt][nt], 0, 0, 0);
    }
    __syncthreads();
  }

  // epilogue: C/D layout col = lane&15, row = quad*4 + reg   (m89/m91)
  const uint2 key = (EPI != 0) ? keys[keyIdx] : make_uint2(0u, 0u);
#pragma unroll
  for (int mt = 0; mt < 2; ++mt)
#pragma unroll
    for (int r = 0; r < 4; ++r) {
      const int gm = m0 + wm + mt * 16 + quad * 4 + r;
      const float ubr = (EPI != 0) ? u[gm] : 0.f;
#pragma unroll
      for (int nt = 0; nt < 2; ++nt) {
        const int gn = n0 + wn + nt * 16 + l15;
        const float val = acc[mt][nt][r];
        if constexpr (EPI == 0 || EPI == 2)
          outA[(size_t)gm * N + gn] = (f16)val;
        if constexpr (EPI == 1 || EPI == 2) {
          float z = (ubr > 0.5f) ? val : (colsum[gn] - val);   // v_branch @ W
          z += cvec[gn];
          float r01 = rng_u01(key, (uint32_t)(gm * N + gn));
          outH[(size_t)gm * N + gn] = (f16)bern_fast(z, r01);
        }
      }
    }
}

// ---------------- fused per-row: dE -> u_new -> v_new ----------------------
__global__ __launch_bounds__(256) void row_uv(
    const f16* __restrict__ a, const f16* __restrict__ v,
    const float* __restrict__ bvec, const float* __restrict__ bsum,
    const uint2* __restrict__ keys, int kU, int kV,
    f16* __restrict__ vout)
{
  __shared__ float s1[4], s2[4], s3[4];
  __shared__ float su;
  const int row = blockIdx.x;
  const int t = threadIdx.x;
  const f16x4  a4 = *(const f16x4*)(a + (size_t)row * Vn + t * 4);
  const float4 bv = ((const float4*)bvec)[t];
  const f16x4  vo = *(const f16x4*)(v + (size_t)row * Vn + t * 4);
  float az[4] = { (float)a4[0], (float)a4[1], (float)a4[2], (float)a4[3] };
  float bz[4] = { bv.x, bv.y, bv.z, bv.w };

  float asum = az[0] + az[1] + az[2] + az[3];
  float va = (float)vo[0]*az[0] + (float)vo[1]*az[1] + (float)vo[2]*az[2] + (float)vo[3]*az[3];
  float vb = (float)vo[0]*bz[0] + (float)vo[1]*bz[1] + (float)vo[2]*bz[2] + (float)vo[3]*bz[3];
#pragma unroll
  for (int off = 32; off > 0; off >>= 1) {
    asum += __shfl_down(asum, off, 64);
    va   += __shfl_down(va,   off, 64);
    vb   += __shfl_down(vb,   off, 64);
  }
  const int wv = t >> 6, ln = t & 63;
  if (ln == 0) { s1[wv] = asum; s2[wv] = va; s3[wv] = vb; }
  __syncthreads();
  if (t == 0) {
    asum = s1[0] + s1[1] + s1[2] + s1[3];
    va   = s2[0] + s2[1] + s2[2] + s2[3];
    vb   = s3[0] + s3[1] + s3[2] + s3[3];
    float dE  = -bsum[0] - asum + 2.f * vb + 2.f * va;
    float r01 = rng_u01(keys[kU], (uint32_t)row);
    su = bern_fast(dE, r01);
  }
  __syncthreads();
  const float un = su;
  const uint2 kv = keys[kV];
  f16x4 vn;
#pragma unroll
  for (int j = 0; j < 4; ++j) {
    float r01 = rng_u01(kv, (uint32_t)(row * Vn + t * 4 + j));
    float x   = bern_fast(az[j] + bz[j], r01);
    vn[j] = (f16)((un > 0.5f) ? x : 1.f - x);
  }
  *(f16x4*)(vout + (size_t)row * Vn + t * 4) = vn;
}

// ------------------------------ free energy --------------------------------
__global__ __launch_bounds__(256) void fe_rows(
    const f16* __restrict__ a, const f16* __restrict__ v,
    const float* __restrict__ bvec, const float* __restrict__ cvec,
    const float* __restrict__ colsum, const float* __restrict__ bsum,
    float* __restrict__ Fout)
{
  __shared__ float s1[4], s2[4], s3[4];
  const int row = blockIdx.x;
  const int t = threadIdx.x;
  const f16x4  a4 = *(const f16x4*)(a + (size_t)row * Hn + t * 4);
  const float4 c4 = ((const float4*)cvec)[t];
  const float4 w4 = ((const float4*)colsum)[t];
  const float4 b4 = ((const float4*)bvec)[t];
  const f16x4  v4 = *(const f16x4*)(v + (size_t)row * Vn + t * 4);

  float mm[4] = { (float)a4[0], (float)a4[1], (float)a4[2], (float)a4[3] };
  float cc[4] = { c4.x, c4.y, c4.z, c4.w };
  float ww[4] = { w4.x, w4.y, w4.z, w4.w };
  float bb[4] = { b4.x, b4.y, b4.z, b4.w };
  float S1 = 0.f, S2 = 0.f, vb = 0.f;
#pragma unroll
  for (int j = 0; j < 4; ++j) {
    S1 += softplus_fast(mm[j] + cc[j]);
    S2 += softplus_fast(ww[j] - mm[j] + cc[j]);
    vb += (float)v4[j] * bb[j];
  }
#pragma unroll
  for (int off = 32; off > 0; off >>= 1) {
    S1 += __shfl_down(S1, off, 64);
    S2 += __shfl_down(S2, off, 64);
    vb += __shfl_down(vb, off, 64);
  }
  const int wv = t >> 6, ln = t & 63;
  if (ln == 0) { s1[wv] = S1; s2[wv] = S2; s3[wv] = vb; }
  __syncthreads();
  if (t == 0) {
    S1 = s1[0] + s1[1] + s1[2] + s1[3];
    S2 = s2[0] + s2[1] + s2[2] + s2[3];
    vb = s3[0] + s3[1] + s3[2] + s3[3];
    float negn = vb - S1;
    float negf = (bsum[0] - vb) - S2;
    float mx = fmaxf(negn, negf);
    Fout[row] = -(mx + logf(expf(negn - mx) + expf(negf - mx)));
  }
}

__global__ __launch_bounds__(256) void finalize_k(
    const float* __restrict__ Fd, const float* __restrict__ Fm, float* __restrict__ out)
{
  __shared__ double sb[8];
  double sd = 0.0, sm = 0.0;
  for (int i = threadIdx.x; i < Bn; i += 256) { sd += (double)Fd[i]; sm += (double)Fm[i]; }
  for (int off = 32; off > 0; off >>= 1) { sd += __shfl_down(sd, off, 64); sm += __shfl_down(sm, off, 64); }
  const int wv = threadIdx.x >> 6, ln = threadIdx.x & 63;
  if (ln == 0) { sb[wv] = sd; sb[4 + wv] = sm; }
  __syncthreads();
  if (threadIdx.x == 0) {
    sd = sb[0] + sb[1] + sb[2] + sb[3];
    sm = sb[4] + sb[5] + sb[6] + sb[7];
    out[0] = (float)((sd - sm) / (double)Bn);
  }
}

// ------------------------------ launch glue --------------------------------
extern "C" void kernel_launch(void* const* d_in, const int* in_sizes, int n_in,
                              void* d_out, int out_size, void* d_ws, size_t ws_size,
                              hipStream_t stream) {
  const float* v_data = (const float*)d_in[0];
  const float* W      = (const float*)d_in[1];
  const float* bvec   = (const float*)d_in[2];
  const float* cvec   = (const float*)d_in[3];
  const int*   seedp  = (const int*)d_in[4];
  float* out = (float*)d_out;

  char* ws = (char*)d_ws;
  size_t off = 0;
  auto alloc = [&](size_t bytes) -> void* {
    void* p = ws + off;
    off += (bytes + 255) & ~(size_t)255;
    return p;
  };
  f16*   v    = (f16*)alloc((size_t)Bn * Vn * 2);     // 16 MB
  f16*   h    = (f16*)alloc((size_t)Bn * Hn * 2);     // 16 MB
  f16*   a    = (f16*)alloc((size_t)Bn * Vn * 2);     // 16 MB
  f16*   Wf   = (f16*)alloc((size_t)Vn * Hn * 2);     // 2 MB  [V][H]
  f16*   WTf  = (f16*)alloc((size_t)Vn * Hn * 2);     // 2 MB  [H][V]
  float* cpart  = (float*)alloc(64 * Hn * 4);         // 256 KB colsum partials
  float* colsum = (float*)alloc(Hn * 4);
  float* bsum   = (float*)alloc(256);
  uint2* keys   = (uint2*)alloc(64 * sizeof(uint2));
  float* u      = (float*)alloc(Bn * 4);
  float* Fd     = (float*)alloc(Bn * 4);
  float* Fm     = (float*)alloc(Bn * 4);
  (void)ws_size; (void)in_sizes; (void)n_in; (void)out_size;

  prep_keys<<<1, 64, 0, stream>>>(seedp, keys);
  colsum_part<<<64, 256, 0, stream>>>(W, cpart);
  colsum_red<<<4, 256, 0, stream>>>(cpart, colsum);
  bsum_k<<<1, 256, 0, stream>>>(bvec, bsum);
  cast_W<<<dim3(Hn / 64, Vn / 64), 256, 0, stream>>>(W, Wf, WTf);
  cast_v<<<(Bn * Vn / 4) / 256, 256, 0, stream>>>(v_data, v);
  u0_init<<<Bn / 256, 256, 0, stream>>>(keys, u);

  dim3 gg(Bn / 64, Hn / 64);   // 128 x 16 = 2048 blocks = 8/CU

  // step 0 fused with F(v_data): writes a = v_data@W AND samples h
  gemm_s<2><<<gg, 256, 0, stream>>>(v, WTf, a, h, u, colsum, cvec, keys, 1);
  fe_rows<<<Bn, 256, 0, stream>>>(a, v, bvec, cvec, colsum, bsum, Fd);
  gemm_s<0><<<gg, 256, 0, stream>>>(h, Wf, a,
                                    nullptr, nullptr, nullptr, nullptr, nullptr, 0);
  row_uv<<<Bn, 256, 0, stream>>>(a, v, bvec, bsum, keys, 2, 3, v);

  for (int s = 1; s < KSTEPS; ++s) {
    gemm_s<1><<<gg, 256, 0, stream>>>(v, WTf, nullptr,
                                      h, u, colsum, cvec, keys, 1 + 3 * s);
    gemm_s<0><<<gg, 256, 0, stream>>>(h, Wf, a,
                                      nullptr, nullptr, nullptr, nullptr, nullptr, 0);
    row_uv<<<Bn, 256, 0, stream>>>(a, v, bvec, bsum, keys, 2 + 3 * s, 3 + 3 * s, v);
  }

  // F(v_model)
  gemm_s<0><<<gg, 256, 0, stream>>>(v, WTf, a,
                                    nullptr, nullptr, nullptr, nullptr, nullptr, 0);
  fe_rows<<<Bn, 256, 0, stream>>>(a, v, bvec, cvec, colsum, bsum, Fm);

  finalize_k<<<1, 256, 0, stream>>>(Fd, Fm, out);
}